// Round 1
// baseline (1797.061 us; speedup 1.0000x reference)
//
#include <hip/hip_runtime.h>
#include <math.h>

#define NEG_SLOPE 0.2f
#define MAXB 1056        // >= nbuckets = ceil(N/64) = 1034 (+slack)
#define BIN_E 4096       // edges per k_bin block
#define HIST_BLKS 512    // histogram blocks fused into k_node dispatch

typedef unsigned short ushort8_v __attribute__((ext_vector_type(8)));
typedef short  short8_v  __attribute__((ext_vector_type(8)));
typedef float  float4_v  __attribute__((ext_vector_type(4)));

__device__ __forceinline__ unsigned short f2bf(float f) {
    unsigned u = __float_as_uint(f);
    u = (u + 0x7FFFu + ((u >> 16) & 1u)) >> 16;    // round-nearest-even
    return (unsigned short)u;
}
__device__ __forceinline__ float bf2f(unsigned short b) {
    return __uint_as_float(((unsigned)b) << 16);
}
__device__ __forceinline__ float lrelu(float x) {
    return x > 0.f ? x : NEG_SLOPE * x;
}

// ---------------------------------------------------------------------------
// K1 (fused): blocks [0, HIST_BLKS): 64-node-bucket histogram of dst.
// Blocks [HIST_BLKS,...): node transform via MFMA (h = x@W bf16, f32 accum)
// + attention logits. 256 thr = 4 waves; wave = 16-node tile (64 nodes/blk).
// hb is now staged in LDS and flushed with coalesced 16B stores (the old
// per-element 2B scatter showed 65.7MB WRITE_SIZE vs ~18MB essential).
// Layouts (verified m89/m91): A[m=lane&15][k=quad*8+j],
// B[k=quad*8+j][n=lane&15], C: col=lane&15, row=quad*4+reg.
// ---------------------------------------------------------------------------
__global__ void k_node_hist(const float* __restrict__ users,
                            const float* __restrict__ items,
                            const float* __restrict__ W,
                            const float* __restrict__ att_src,
                            const float* __restrict__ att_dst,
                            unsigned short* __restrict__ hb,
                            float* __restrict__ a_src,
                            float* __restrict__ a_dst,
                            const int* __restrict__ dst,
                            int* __restrict__ bcnt,
                            int nedges, int nbuckets,
                            int n_users, int N)
{
    // 16KB tile; hist blocks reuse it as int[] histogram (needs 4.2KB)
    __shared__ __align__(16) unsigned short tile[64][128];

    if (blockIdx.x < HIST_BLKS) {
        int* hsh = (int*)&tile[0][0];
        for (int i = threadIdx.x; i < nbuckets; i += 256) hsh[i] = 0;
        __syncthreads();
        for (int i = blockIdx.x * 256 + threadIdx.x; i < nedges;
             i += HIST_BLKS * 256)
            atomicAdd(&hsh[dst[i] >> 6], 1);
        __syncthreads();
        for (int i = threadIdx.x; i < nbuckets; i += 256)
            if (hsh[i]) atomicAdd(&bcnt[i], hsh[i]);
        return;
    }

    // ---- node transform part ----
    const int blk  = blockIdx.x - HIST_BLKS;
    const int wid  = threadIdx.x >> 6;       // wave 0..3
    const int lane = threadIdx.x & 63;
    const int quad = lane >> 4;              // 0..3
    const int l16  = lane & 15;
    const int tb   = blk * 64 + wid * 16;    // tile base node

    // B fragments: bfrag[t][h2] holds W[k = h2*32+quad*8+j][t*16 + l16]
    short8_v bfrag[8][2];
    #pragma unroll
    for (int t = 0; t < 8; ++t)
        #pragma unroll
        for (int h2 = 0; h2 < 2; ++h2)
            #pragma unroll
            for (int j = 0; j < 8; ++j)
                bfrag[t][h2][j] = (short)f2bf(
                    W[(h2 * 32 + quad * 8 + j) * 128 + t * 16 + l16]);

    float atts[8], attd[8];
    #pragma unroll
    for (int t = 0; t < 8; ++t) {
        atts[t] = att_src[t * 16 + l16];
        attd[t] = att_dst[t * 16 + l16];
    }

    const int arow = tb + l16;
    short8_v a0 = (short8_v)0, a1 = (short8_v)0;
    if (arow < N) {
        const float* xr = (arow < n_users)
            ? (users + (size_t)arow * 64)
            : (items + (size_t)(arow - n_users) * 64);
        const float4_v x0 = *reinterpret_cast<const float4_v*>(xr + quad * 8);
        const float4_v x1 = *reinterpret_cast<const float4_v*>(xr + quad * 8 + 4);
        const float4_v x2 = *reinterpret_cast<const float4_v*>(xr + 32 + quad * 8);
        const float4_v x3 = *reinterpret_cast<const float4_v*>(xr + 32 + quad * 8 + 4);
        #pragma unroll
        for (int j = 0; j < 4; ++j) {
            a0[j]     = (short)f2bf(x0[j]);
            a0[j + 4] = (short)f2bf(x1[j]);
            a1[j]     = (short)f2bf(x2[j]);
            a1[j + 4] = (short)f2bf(x3[j]);
        }
    }

    float4_v acc[8];
    #pragma unroll
    for (int t = 0; t < 8; ++t) {
        acc[t] = (float4_v)0.f;
        acc[t] = __builtin_amdgcn_mfma_f32_16x16x32_bf16(a0, bfrag[t][0], acc[t], 0, 0, 0);
        acc[t] = __builtin_amdgcn_mfma_f32_16x16x32_bf16(a1, bfrag[t][1], acc[t], 0, 0, 0);
    }

    const int wrow0 = tb + quad * 4;
    float s0[4] = {0,0,0,0}, s1[4] = {0,0,0,0};
    float d0[4] = {0,0,0,0}, d1[4] = {0,0,0,0};
    #pragma unroll
    for (int t = 0; t < 8; ++t) {
        #pragma unroll
        for (int r = 0; r < 4; ++r) {
            const float v = acc[t][r];
            if (t < 4) { s0[r] = fmaf(v, atts[t], s0[r]);
                         d0[r] = fmaf(v, attd[t], d0[r]); }
            else       { s1[r] = fmaf(v, atts[t], s1[r]);
                         d1[r] = fmaf(v, attd[t], d1[r]); }
            tile[wid * 16 + quad * 4 + r][t * 16 + l16] = f2bf(v);
        }
    }

    #pragma unroll
    for (int off = 1; off < 16; off <<= 1) {
        #pragma unroll
        for (int r = 0; r < 4; ++r) {
            s0[r] += __shfl_xor(s0[r], off);
            s1[r] += __shfl_xor(s1[r], off);
            d0[r] += __shfl_xor(d0[r], off);
            d1[r] += __shfl_xor(d1[r], off);
        }
    }
    if (l16 == 0) {
        #pragma unroll
        for (int r = 0; r < 4; ++r) {
            const int row = wrow0 + r;
            if (row < N) {
                a_src[row * 2]     = s0[r];
                a_src[row * 2 + 1] = s1[r];
                a_dst[row * 2]     = d0[r];
                a_dst[row * 2 + 1] = d1[r];
            }
        }
    }

    // coalesced hb flush: 16B per lane
    __syncthreads();
    const int nrem = min(64, N - blk * 64);
    for (int k = threadIdx.x; k < nrem * 16; k += 256) {
        const int n = k >> 4, g = k & 15;
        *reinterpret_cast<ushort8_v*>(hb + (size_t)(blk * 64 + n) * 128 + g * 8) =
            *reinterpret_cast<const ushort8_v*>(&tile[n][g * 8]);
    }
}

// ---------------------------------------------------------------------------
// K2: exclusive scan of bcnt -> bucket_base AND tails. Single wave.
// Also writes bucket_base[nbuckets] = E.
// ---------------------------------------------------------------------------
__global__ void k_bscan(const int* __restrict__ bcnt,
                        int* __restrict__ bucket_base,
                        int* __restrict__ tails,
                        int nbuckets, int E)
{
    const int lane = threadIdx.x;          // 64 threads
    int running = 0;
    for (int base = 0; base < nbuckets; base += 64) {
        int idx = base + lane;
        int v = (idx < nbuckets) ? bcnt[idx] : 0;
        int incl = v;
        #pragma unroll
        for (int off = 1; off < 64; off <<= 1) {
            int t = __shfl_up(incl, off);
            if (lane >= off) incl += t;
        }
        if (idx < nbuckets) {
            int ex = running + incl - v;
            bucket_base[idx] = ex;
            tails[idx]       = ex;
        }
        running += __shfl(incl, 63);
    }
    if (lane == 0) bucket_base[nbuckets] = E;
}

// ---------------------------------------------------------------------------
// K3: bin pass, 512 thr. Records are now 4B pure permutation payloads:
//   rec = src | (dst & 63) << 17      (src < 2^17, 64-node buckets)
// No a_src/a_dst gather, no exp — that moved into k_bucket (f32 end-to-end).
// LDS counting-sort by bucket, one atomic tail bump per bucket +
// contiguous burst write.
// ---------------------------------------------------------------------------
__global__ void k_bin(const int* __restrict__ src, const int* __restrict__ dst,
                      int* __restrict__ tails,
                      int* __restrict__ stage_g,
                      int nedges, int nbuckets)
{
    __shared__ int cnt[MAXB];
    __shared__ int runoff[MAXB];
    __shared__ int cursor[MAXB];
    __shared__ int runbase[MAXB];
    __shared__ int stage[BIN_E];
    __shared__ unsigned short sb[BIN_E];

    const int tid  = threadIdx.x;          // 0..511
    const int lane = tid & 63;
    const int wid  = tid >> 6;             // 0..7
    const int base = blockIdx.x * BIN_E;
    const int nvalid = min(BIN_E, nedges - base);

    for (int i = tid; i < nbuckets; i += 512) cnt[i] = 0;
    __syncthreads();

    int myrec[BIN_E / 512];
    int myb[BIN_E / 512];
    #pragma unroll
    for (int k = 0; k < BIN_E / 512; ++k) {
        int i = base + k * 512 + tid;
        if (i < nedges) {
            int d = dst[i];
            int s = src[i];
            myrec[k] = s | ((d & 63) << 17);
            int b = d >> 6;
            myb[k] = b;
            atomicAdd(&cnt[b], 1);
        } else {
            myb[k] = -1;
        }
    }
    __syncthreads();

    // wave 0: exclusive scan cnt -> runoff
    if (wid == 0) {
        int running = 0;
        for (int b2 = 0; b2 < nbuckets; b2 += 64) {
            int idx = b2 + lane;
            int v = (idx < nbuckets) ? cnt[idx] : 0;
            int incl = v;
            #pragma unroll
            for (int off = 1; off < 64; off <<= 1) {
                int t = __shfl_up(incl, off);
                if (lane >= off) incl += t;
            }
            if (idx < nbuckets) runoff[idx] = running + incl - v;
            running += __shfl(incl, 63);
        }
    }
    __syncthreads();

    for (int i = tid; i < nbuckets; i += 512) cursor[i] = runoff[i];
    __syncthreads();

    #pragma unroll
    for (int k = 0; k < BIN_E / 512; ++k) {
        if (myb[k] >= 0) {
            int pos = atomicAdd(&cursor[myb[k]], 1);
            stage[pos] = myrec[k];
            sb[pos] = (unsigned short)myb[k];
        }
    }

    for (int i = tid; i < nbuckets; i += 512)
        if (cnt[i] > 0) runbase[i] = atomicAdd(&tails[i], cnt[i]);
    __syncthreads();

    for (int i = tid; i < nvalid; i += 512) {
        int b = sb[i];
        stage_g[runbase[b] + (i - runoff[b])] = stage[i];
    }
}

// ---------------------------------------------------------------------------
// K4 (replaces old refine+gather): one block per 64-node bucket.
// acc[64][128] f32 lives in LDS, channel-swizzled so the 16-lane group's
// 8 ds_add_f32 per edge are bank-conflict-free:
//   store channel c of node n at  acc[n*129 + (c&7)*16 + (c>>3)]
//   (lane sl owns c = sl*8+j  ->  index j*16+sl; row stride 129 rotates
//    banks per node so concurrent groups rarely collide).
// Edge exp recomputed here in f32 (a_src gather is L2-resident: 0.5MB).
// Self-loop = accumulator init (no atomics). den accumulated in LDS too.
// 34KB LDS -> 4 blocks/CU, 16 waves/CU.
// ---------------------------------------------------------------------------
__global__ void k_bucket(const int* __restrict__ stage_g,
                         const int* __restrict__ bucket_base,
                         const float* __restrict__ a_src,
                         const float* __restrict__ a_dst,
                         const unsigned short* __restrict__ hb,
                         const float* __restrict__ bias,
                         float* __restrict__ out,
                         int N)
{
    __shared__ float acc[64 * 129];        // swizzled, 33KB
    __shared__ float den[64][2];
    __shared__ float adst[64][2];

    const int b      = blockIdx.x;
    const int node0  = b << 6;
    const int nnodes = min(64, N - node0);
    const int tid    = threadIdx.x;        // 0..255

    // phase 0: per-node a_dst + self-loop exp (den init)
    if (tid < 64) {
        if (tid < nnodes) {
            const int node = node0 + tid;
            const float2 as = *reinterpret_cast<const float2*>(a_src + 2 * node);
            const float2 ad = *reinterpret_cast<const float2*>(a_dst + 2 * node);
            adst[tid][0] = ad.x;
            adst[tid][1] = ad.y;
            den[tid][0] = __expf(lrelu(as.x + ad.x));
            den[tid][1] = __expf(lrelu(as.y + ad.y));
        } else {
            adst[tid][0] = adst[tid][1] = 0.f;
            den[tid][0]  = den[tid][1]  = 0.f;
        }
    }
    __syncthreads();

    // phase 1: acc init = self-loop contribution (den holds ex_self here)
    for (int k = tid; k < nnodes * 16; k += 256) {
        const int n = k >> 4, g = k & 15;
        const float e = den[n][g >> 3];
        const ushort8_v hv = *reinterpret_cast<const ushort8_v*>(
            hb + (size_t)(node0 + n) * 128 + g * 8);
        #pragma unroll
        for (int j = 0; j < 8; ++j)
            acc[n * 129 + j * 16 + g] = e * bf2f(hv[j]);
    }
    __syncthreads();

    // phase 2: edge loop. 16 groups of 16 lanes; group = one edge.
    const int grp = tid >> 4;
    const int sl  = tid & 15;              // channel group: 8 ch each
    const int hd  = sl >> 3;               // head of those channels
    const bool denlane = ((sl & 7) == 0);
    const int lo = bucket_base[b];
    const int hi = bucket_base[b + 1];

    #pragma unroll 4
    for (int e = lo + grp; e < hi; e += 16) {
        const int rec = stage_g[e];
        const int s = rec & 0x1FFFF;
        const int n = (rec >> 17) & 63;
        const float2 as2 = *reinterpret_cast<const float2*>(a_src + 2 * s);
        const float ex = __expf(lrelu((hd ? as2.y : as2.x) + adst[n][hd]));
        const ushort8_v hv = *reinterpret_cast<const ushort8_v*>(
            hb + (size_t)s * 128 + sl * 8);
        if (denlane) unsafeAtomicAdd(&den[n][hd], ex);
        #pragma unroll
        for (int j = 0; j < 8; ++j)
            unsafeAtomicAdd(&acc[n * 129 + j * 16 + sl], ex * bf2f(hv[j]));
    }
    __syncthreads();

    // phase 3: normalize + bias, coalesced float4 out
    for (int k = tid; k < nnodes * 32; k += 256) {
        const int n = k >> 5, m = k & 31;
        const float inv = 1.f / (den[n][m >> 4] + 1e-16f);
        const float4_v bv = *reinterpret_cast<const float4_v*>(bias + m * 4);
        float4_v o;
        #pragma unroll
        for (int j = 0; j < 4; ++j) {
            const int c = m * 4 + j;
            o[j] = acc[n * 129 + (c & 7) * 16 + (c >> 3)] * inv + bv[j];
        }
        *reinterpret_cast<float4_v*>(out + (size_t)(node0 + n) * 128 + m * 4) = o;
    }
}

extern "C" void kernel_launch(void* const* d_in, const int* in_sizes, int n_in,
                              void* d_out, int out_size, void* d_ws, size_t ws_size,
                              hipStream_t stream) {
    const int*   edge  = (const int*)  d_in[0];   // (2,E) int32
    const float* users = (const float*)d_in[1];   // (N_USERS,64) f32
    const float* items = (const float*)d_in[2];   // (N_ITEMS,64) f32
    const float* W     = (const float*)d_in[3];   // (64,128) f32
    const float* att_s = (const float*)d_in[4];   // (2,64) f32
    const float* att_d = (const float*)d_in[5];   // (2,64) f32
    const float* bias  = (const float*)d_in[6];   // (128,) f32

    const int E       = in_sizes[0] / 2;
    const int n_users = in_sizes[1] / 64;
    const int n_items = in_sizes[2] / 64;
    const int N       = n_users + n_items;
    const int nbuckets = (N + 63) >> 6;           // 1034

    float* out = (float*)d_out;

    // Workspace layout (alignment maintained):
    // hb (N*128 bf16) | stage (E int) | a_src | a_dst | bcnt | bucket_base | tails
    char* ws = (char*)d_ws;
    unsigned short* hb = (unsigned short*)ws;
    ws += (size_t)N * 128 * sizeof(unsigned short);
    int*   stage    = (int*)ws;    ws += (size_t)E * sizeof(int);
    float* a_src    = (float*)ws;  ws += (size_t)N * 2 * sizeof(float);
    float* a_dst    = (float*)ws;  ws += (size_t)N * 2 * sizeof(float);
    int*   bcnt     = (int*)ws;    ws += MAXB * sizeof(int);
    int*   bucket_base = (int*)ws; ws += (MAXB + 1) * sizeof(int);
    int*   tails    = (int*)ws;

    const int* src = edge;
    const int* dst = edge + E;

    hipMemsetAsync(bcnt, 0, MAXB * sizeof(int), stream);

    const int node_blocks = (N + 63) / 64;
    k_node_hist<<<HIST_BLKS + node_blocks, 256, 0, stream>>>(
        users, items, W, att_s, att_d, hb, a_src, a_dst,
        dst, bcnt, E, nbuckets, n_users, N);

    k_bscan<<<1, 64, 0, stream>>>(bcnt, bucket_base, tails, nbuckets, E);

    k_bin<<<(E + BIN_E - 1) / BIN_E, 512, 0, stream>>>(
        src, dst, tails, stage, E, nbuckets);

    k_bucket<<<nbuckets, 256, 0, stream>>>(stage, bucket_base, a_src, a_dst,
                                           hb, bias, out, N);
}

// Round 2
// 284.992 us; speedup vs baseline: 6.3056x; 6.3056x over previous
//
#include <hip/hip_runtime.h>
#include <hip/hip_fp16.h>
#include <math.h>

#define NEG_SLOPE 0.2f
#define MAXB 512         // max buckets (N up to 131072); actual 259
#define BIN_E 2048       // edges per k_bin block
#define HIST_BLKS 512    // histogram blocks fused into k_node dispatch

typedef unsigned short ushort8_v __attribute__((ext_vector_type(8)));
typedef short  short8_v  __attribute__((ext_vector_type(8)));
typedef float  float4_v  __attribute__((ext_vector_type(4)));

__device__ __forceinline__ unsigned short f2bf(float f) {
    unsigned u = __float_as_uint(f);
    u = (u + 0x7FFFu + ((u >> 16) & 1u)) >> 16;    // round-nearest-even
    return (unsigned short)u;
}
__device__ __forceinline__ float bf2f(unsigned short b) {
    return __uint_as_float(((unsigned)b) << 16);
}
__device__ __forceinline__ float lrelu(float x) {
    return x > 0.f ? x : NEG_SLOPE * x;
}
__device__ __forceinline__ unsigned f2h_bits(float f) {
    __half_raw hr = __half_raw(__float2half_rn(f));
    return (unsigned)hr.x;
}
__device__ __forceinline__ float h2f_bits(unsigned short u) {
    __half_raw hr; hr.x = u;
    return __half2float(__half(hr));
}

// ---------------------------------------------------------------------------
// K1 (fused): blocks [0, HIST_BLKS): bucket histogram of dst (BW-bound,
// streams while MFMA blocks compute). Blocks [HIST_BLKS, ...): node
// transform via MFMA (h = x@W bf16, f32 accum) + attention logits.
// Node part: 256 thr = 4 waves; wave = 16-node tile (64 nodes/block).
// hb is staged in LDS (padded [64][130] -> <=4-way bank aliasing on the
// 2B stores) and flushed with coalesced 16B ushort8 stores. Round-0
// counters showed 65.7MB WRITE_SIZE vs ~18MB essential from the old
// per-element 2B scatter (32B segments at 256B stride).
// Layouts (verified m89/m91/m120): A[m=lane&15][k=quad*8+j],
// B[k=quad*8+j][n=lane&15], C: col=lane&15, row=quad*4+reg.
// ---------------------------------------------------------------------------
__global__ void k_node_hist(const float* __restrict__ users,
                            const float* __restrict__ items,
                            const float* __restrict__ W,
                            const float* __restrict__ att_src,
                            const float* __restrict__ att_dst,
                            unsigned short* __restrict__ hb,
                            float* __restrict__ a_src,
                            float* __restrict__ a_dst,
                            const int* __restrict__ dst,
                            int* __restrict__ bcnt,
                            int nedges, int nbuckets,
                            int n_users, int N)
{
    // 16.6KB tile; hist blocks reuse it as int[] histogram (needs 2KB)
    __shared__ __align__(16) unsigned short tile[64][130];

    if (blockIdx.x < HIST_BLKS) {
        // ---- histogram part ----
        int* hsh = (int*)&tile[0][0];
        for (int i = threadIdx.x; i < nbuckets; i += 256) hsh[i] = 0;
        __syncthreads();
        for (int i = blockIdx.x * 256 + threadIdx.x; i < nedges;
             i += HIST_BLKS * 256)
            atomicAdd(&hsh[dst[i] >> 8], 1);
        __syncthreads();
        for (int i = threadIdx.x; i < nbuckets; i += 256)
            if (hsh[i]) atomicAdd(&bcnt[i], hsh[i]);
        return;
    }

    // ---- node transform part ----
    const int blk  = blockIdx.x - HIST_BLKS;
    const int wid  = threadIdx.x >> 6;       // wave 0..3
    const int lane = threadIdx.x & 63;
    const int quad = lane >> 4;              // 0..3
    const int l16  = lane & 15;
    const int tb   = blk * 64 + wid * 16;    // tile base node

    // B fragments: bfrag[t][h2] holds W[k = h2*32+quad*8+j][t*16 + l16]
    short8_v bfrag[8][2];
    #pragma unroll
    for (int t = 0; t < 8; ++t)
        #pragma unroll
        for (int h2 = 0; h2 < 2; ++h2)
            #pragma unroll
            for (int j = 0; j < 8; ++j)
                bfrag[t][h2][j] = (short)f2bf(
                    W[(h2 * 32 + quad * 8 + j) * 128 + t * 16 + l16]);

    float atts[8], attd[8];
    #pragma unroll
    for (int t = 0; t < 8; ++t) {
        atts[t] = att_src[t * 16 + l16];
        attd[t] = att_dst[t * 16 + l16];
    }

    const int arow = tb + l16;
    short8_v a0 = (short8_v)0, a1 = (short8_v)0;
    if (arow < N) {
        const float* xr = (arow < n_users)
            ? (users + (size_t)arow * 64)
            : (items + (size_t)(arow - n_users) * 64);
        const float4_v x0 = *reinterpret_cast<const float4_v*>(xr + quad * 8);
        const float4_v x1 = *reinterpret_cast<const float4_v*>(xr + quad * 8 + 4);
        const float4_v x2 = *reinterpret_cast<const float4_v*>(xr + 32 + quad * 8);
        const float4_v x3 = *reinterpret_cast<const float4_v*>(xr + 32 + quad * 8 + 4);
        #pragma unroll
        for (int j = 0; j < 4; ++j) {
            a0[j]     = (short)f2bf(x0[j]);
            a0[j + 4] = (short)f2bf(x1[j]);
            a1[j]     = (short)f2bf(x2[j]);
            a1[j + 4] = (short)f2bf(x3[j]);
        }
    }

    float4_v acc[8];
    #pragma unroll
    for (int t = 0; t < 8; ++t) {
        acc[t] = (float4_v)0.f;
        acc[t] = __builtin_amdgcn_mfma_f32_16x16x32_bf16(a0, bfrag[t][0], acc[t], 0, 0, 0);
        acc[t] = __builtin_amdgcn_mfma_f32_16x16x32_bf16(a1, bfrag[t][1], acc[t], 0, 0, 0);
    }

    const int wrow0 = tb + quad * 4;
    float s0[4] = {0,0,0,0}, s1[4] = {0,0,0,0};
    float d0[4] = {0,0,0,0}, d1[4] = {0,0,0,0};
    #pragma unroll
    for (int t = 0; t < 8; ++t) {
        #pragma unroll
        for (int r = 0; r < 4; ++r) {
            const float v = acc[t][r];
            if (t < 4) { s0[r] = fmaf(v, atts[t], s0[r]);
                         d0[r] = fmaf(v, attd[t], d0[r]); }
            else       { s1[r] = fmaf(v, atts[t], s1[r]);
                         d1[r] = fmaf(v, attd[t], d1[r]); }
            tile[wid * 16 + quad * 4 + r][t * 16 + l16] = f2bf(v);
        }
    }

    #pragma unroll
    for (int off = 1; off < 16; off <<= 1) {
        #pragma unroll
        for (int r = 0; r < 4; ++r) {
            s0[r] += __shfl_xor(s0[r], off);
            s1[r] += __shfl_xor(s1[r], off);
            d0[r] += __shfl_xor(d0[r], off);
            d1[r] += __shfl_xor(d1[r], off);
        }
    }
    if (l16 == 0) {
        #pragma unroll
        for (int r = 0; r < 4; ++r) {
            const int row = wrow0 + r;
            if (row < N) {
                a_src[row * 2]     = s0[r];
                a_src[row * 2 + 1] = s1[r];
                a_dst[row * 2]     = d0[r];
                a_dst[row * 2 + 1] = d1[r];
            }
        }
    }

    // coalesced hb flush: 16B per lane, contiguous 1KB per 64 lanes
    __syncthreads();
    const int nrem = min(64, N - blk * 64);
    for (int k = threadIdx.x; k < nrem * 16; k += 256) {
        const int n = k >> 4, g = k & 15;
        ushort8_v v;
        #pragma unroll
        for (int j = 0; j < 8; ++j) v[j] = tile[n][g * 8 + j];
        *reinterpret_cast<ushort8_v*>(
            hb + (size_t)(blk * 64 + n) * 128 + g * 8) = v;
    }
}

// ---------------------------------------------------------------------------
// K2: exclusive scan of bcnt -> bucket_base AND tails. Single wave.
// Also writes rowptr[N] = E.
// ---------------------------------------------------------------------------
__global__ void k_bscan(const int* __restrict__ bcnt,
                        int* __restrict__ bucket_base,
                        int* __restrict__ tails,
                        int* __restrict__ rowptr,
                        int nbuckets, int N, int E)
{
    const int lane = threadIdx.x;          // 64 threads
    int running = 0;
    for (int base = 0; base < nbuckets; base += 64) {
        int idx = base + lane;
        int v = (idx < nbuckets) ? bcnt[idx] : 0;
        int incl = v;
        #pragma unroll
        for (int off = 1; off < 64; off <<= 1) {
            int t = __shfl_up(incl, off);
            if (lane >= off) incl += t;
        }
        if (idx < nbuckets) {
            int ex = running + incl - v;
            bucket_base[idx] = ex;
            tails[idx]       = ex;
        }
        running += __shfl(incl, 63);
    }
    if (lane == 0) rowptr[N] = E;
}

// ---------------------------------------------------------------------------
// K3: bin pass, 512 thr (8 waves — hides a_src/a_dst gather latency).
// Each block: read 2048 edges ONCE, build packed records
//   rec.x = (ex1_h<<16)|ex0_h, rec.y = src | (dst&255)<<17
// LDS counting-sort by bucket, one atomic tail bump per bucket +
// contiguous burst write.
// ---------------------------------------------------------------------------
__global__ void k_bin(const int* __restrict__ src, const int* __restrict__ dst,
                      const float* __restrict__ a_src,
                      const float* __restrict__ a_dst,
                      int* __restrict__ tails,
                      int2* __restrict__ stage_g,
                      int nedges, int nbuckets)
{
    __shared__ int cnt[MAXB];
    __shared__ int runoff[MAXB];
    __shared__ int cursor[MAXB];
    __shared__ int runbase[MAXB];
    __shared__ int2 stage[BIN_E];
    __shared__ unsigned short sb[BIN_E];

    const int tid  = threadIdx.x;          // 0..511
    const int lane = tid & 63;
    const int wid  = tid >> 6;             // 0..7
    const int base = blockIdx.x * BIN_E;
    const int nvalid = min(BIN_E, nedges - base);

    for (int i = tid; i < nbuckets; i += 512) cnt[i] = 0;
    __syncthreads();

    int2 myrec[BIN_E / 512];
    int  myb[BIN_E / 512];
    #pragma unroll
    for (int k = 0; k < BIN_E / 512; ++k) {
        int i = base + k * 512 + tid;
        if (i < nedges) {
            int d = dst[i];
            int s = src[i];
            const float2 as2 = *reinterpret_cast<const float2*>(a_src + 2 * s);
            const float2 ad2 = *reinterpret_cast<const float2*>(a_dst + 2 * d);
            unsigned e0 = f2h_bits(__expf(lrelu(as2.x + ad2.x)));
            unsigned e1 = f2h_bits(__expf(lrelu(as2.y + ad2.y)));
            myrec[k].x = (int)((e1 << 16) | e0);
            myrec[k].y = s | ((d & 255) << 17);
            int b = d >> 8;
            myb[k] = b;
            atomicAdd(&cnt[b], 1);
        } else {
            myb[k] = -1;
        }
    }
    __syncthreads();

    // wave 0: exclusive scan cnt -> runoff
    if (wid == 0) {
        int running = 0;
        for (int b2 = 0; b2 < nbuckets; b2 += 64) {
            int idx = b2 + lane;
            int v = (idx < nbuckets) ? cnt[idx] : 0;
            int incl = v;
            #pragma unroll
            for (int off = 1; off < 64; off <<= 1) {
                int t = __shfl_up(incl, off);
                if (lane >= off) incl += t;
            }
            if (idx < nbuckets) runoff[idx] = running + incl - v;
            running += __shfl(incl, 63);
        }
    }
    __syncthreads();

    for (int i = tid; i < nbuckets; i += 512) cursor[i] = runoff[i];
    __syncthreads();

    #pragma unroll
    for (int k = 0; k < BIN_E / 512; ++k) {
        if (myb[k] >= 0) {
            int pos = atomicAdd(&cursor[myb[k]], 1);
            stage[pos] = myrec[k];
            sb[pos] = (unsigned short)myb[k];
        }
    }

    for (int i = tid; i < nbuckets; i += 512)
        if (cnt[i] > 0) runbase[i] = atomicAdd(&tails[i], cnt[i]);
    __syncthreads();

    for (int i = tid; i < nvalid; i += 512) {
        int b = sb[i];
        stage_g[runbase[b] + (i - runoff[b])] = stage[i];
    }
}

// ---------------------------------------------------------------------------
// K4: refine, 1024 thr (16 waves). One block per bucket (256 nodes):
// histogram records over 256 node slots (rowptr falls out free), scan,
// scatter into exact per-dst CSR order.
// ---------------------------------------------------------------------------
__global__ void k_refine(const int2* __restrict__ stage_g,
                         const int* __restrict__ bucket_base,
                         int* __restrict__ rowptr,
                         int2* __restrict__ recs,
                         int N, int E, int nbuckets)
{
    const int b   = blockIdx.x;
    const int tid = threadIdx.x;           // 0..1023
    const int lane = tid & 63;
    const int wid  = tid >> 6;
    const int lo = bucket_base[b];
    const int hi = (b + 1 < nbuckets) ? bucket_base[b + 1] : E;
    const int node0  = b << 8;
    const int nnodes = min(256, N - node0);

    __shared__ int cnt[256];
    __shared__ int off[256];
    __shared__ int cursor[256];

    if (tid < 256) cnt[tid] = 0;
    __syncthreads();

    for (int i = lo + tid; i < hi; i += 1024) {
        int dlow = (stage_g[i].y >> 17) & 255;
        atomicAdd(&cnt[dlow], 1);
    }
    __syncthreads();

    if (wid == 0) {
        int running = 0;
        for (int b2 = 0; b2 < 256; b2 += 64) {
            int idx = b2 + lane;
            int v = cnt[idx];
            int incl = v;
            #pragma unroll
            for (int o = 1; o < 64; o <<= 1) {
                int t = __shfl_up(incl, o);
                if (lane >= o) incl += t;
            }
            off[idx] = running + incl - v;
            running += __shfl(incl, 63);
        }
    }
    __syncthreads();

    if (tid < nnodes) rowptr[node0 + tid] = lo + off[tid];
    if (tid < 256) cursor[tid] = lo + off[tid];
    __syncthreads();

    for (int i = lo + tid; i < hi; i += 1024) {
        int2 r = stage_g[i];
        int dlow = (r.y >> 17) & 255;
        int pos = atomicAdd(&cursor[dlow], 1);
        recs[pos] = r;
    }
}

// ---------------------------------------------------------------------------
// K5: gather-accumulate. One wave per node; quarter-wave (16 lanes) per
// edge, 4 edges in flight (+unroll 4 for deeper MLP). Lane sl owns
// channels sl*8..sl*8+7 (ushort8 = 16 B, 256 B coalesced row per quarter).
// Self-loop = virtual edge 0.
// ---------------------------------------------------------------------------
__global__ void k_gather(const int* __restrict__ rowptr,
                         const int2* __restrict__ recs,
                         const float* __restrict__ a_src,
                         const float* __restrict__ a_dst,
                         const unsigned short* __restrict__ hb,
                         const float* __restrict__ bias,
                         float* __restrict__ out,
                         int nnodes)
{
    const int d = blockIdx.x * 4 + (threadIdx.x >> 6);  // wave per node
    if (d >= nnodes) return;
    const int lane = threadIdx.x & 63;
    const int q    = lane >> 4;            // quarter: which edge of the 4
    const int sl   = lane & 15;            // channel group: 8 ch each
    const int hd   = sl >> 3;              // head of those channels

    const float2 as2 = *reinterpret_cast<const float2*>(a_src + 2 * d);
    const float2 ad2 = *reinterpret_cast<const float2*>(a_dst + 2 * d);
    const float exs0 = __expf(lrelu(as2.x + ad2.x));
    const float exs1 = __expf(lrelu(as2.y + ad2.y));

    const int start = rowptr[d];
    const int cnt1  = rowptr[d + 1] - start + 1;   // +1 for self loop

    float acc[8];
    #pragma unroll
    for (int i = 0; i < 8; ++i) acc[i] = 0.f;
    float den = 0.f;

    #pragma unroll 4
    for (int v = q; v < cnt1; v += 4) {
        int s; float ex;
        if (v == 0) {
            s = d;  ex = hd ? exs1 : exs0;
        } else {
            const int2 r = recs[start + v - 1];
            s = r.y & 0x1FFFF;
            const unsigned eb = (unsigned)r.x;
            ex = h2f_bits(hd ? (unsigned short)(eb >> 16)
                             : (unsigned short)(eb & 0xFFFFu));
        }
        const ushort8_v hv = *reinterpret_cast<const ushort8_v*>(
            hb + (size_t)s * 128 + sl * 8);
        den += ex;
        #pragma unroll
        for (int i = 0; i < 8; ++i)
            acc[i] = fmaf(ex, bf2f(hv[i]), acc[i]);
    }

    // merge the four quarter accumulators
    #pragma unroll
    for (int off = 16; off <= 32; off <<= 1) {
        #pragma unroll
        for (int i = 0; i < 8; ++i) acc[i] += __shfl_xor(acc[i], off);
        den += __shfl_xor(den, off);
    }

    if (q == 0) {
        const float inv = 1.f / (den + 1e-16f);
        float4 o0, o1;
        o0.x = acc[0] * inv + bias[sl * 8 + 0];
        o0.y = acc[1] * inv + bias[sl * 8 + 1];
        o0.z = acc[2] * inv + bias[sl * 8 + 2];
        o0.w = acc[3] * inv + bias[sl * 8 + 3];
        o1.x = acc[4] * inv + bias[sl * 8 + 4];
        o1.y = acc[5] * inv + bias[sl * 8 + 5];
        o1.z = acc[6] * inv + bias[sl * 8 + 6];
        o1.w = acc[7] * inv + bias[sl * 8 + 7];
        float* op = out + (size_t)d * 128 + sl * 8;
        *reinterpret_cast<float4*>(op)     = o0;
        *reinterpret_cast<float4*>(op + 4) = o1;
    }
}

extern "C" void kernel_launch(void* const* d_in, const int* in_sizes, int n_in,
                              void* d_out, int out_size, void* d_ws, size_t ws_size,
                              hipStream_t stream) {
    const int*   edge  = (const int*)  d_in[0];   // (2,E) int32
    const float* users = (const float*)d_in[1];   // (N_USERS,64) f32
    const float* items = (const float*)d_in[2];   // (N_ITEMS,64) f32
    const float* W     = (const float*)d_in[3];   // (64,128) f32
    const float* att_s = (const float*)d_in[4];   // (2,64) f32
    const float* att_d = (const float*)d_in[5];   // (2,64) f32
    const float* bias  = (const float*)d_in[6];   // (128,) f32

    const int E       = in_sizes[0] / 2;
    const int n_users = in_sizes[1] / 64;
    const int n_items = in_sizes[2] / 64;
    const int N       = n_users + n_items;
    const int nbuckets = (N + 255) >> 8;          // 259

    float* out = (float*)d_out;

    // Workspace layout (8-B alignment maintained):
    // hb (N*128 bf16) | stage (E int2) | recs (E int2) | a_src | a_dst
    // | rowptr (N+1) | bcnt | bucket_base | tails
    char* ws = (char*)d_ws;
    unsigned short* hb = (unsigned short*)ws;
    ws += (size_t)N * 128 * sizeof(unsigned short);
    int2*  stage    = (int2*)ws;   ws += (size_t)E * sizeof(int2);
    int2*  recs     = (int2*)ws;   ws += (size_t)E * sizeof(int2);
    float* a_src    = (float*)ws;  ws += (size_t)N * 2 * sizeof(float);
    float* a_dst    = (float*)ws;  ws += (size_t)N * 2 * sizeof(float);
    int*   rowptr   = (int*)ws;    ws += (size_t)(N + 1) * sizeof(int);
    int*   bcnt     = (int*)ws;    ws += MAXB * sizeof(int);
    int*   bucket_base = (int*)ws; ws += MAXB * sizeof(int);
    int*   tails    = (int*)ws;

    const int* src = edge;
    const int* dst = edge + E;

    hipMemsetAsync(bcnt, 0, MAXB * sizeof(int), stream);

    const int node_blocks = (N + 63) / 64;
    k_node_hist<<<HIST_BLKS + node_blocks, 256, 0, stream>>>(
        users, items, W, att_s, att_d, hb, a_src, a_dst,
        dst, bcnt, E, nbuckets, n_users, N);

    k_bscan<<<1, 64, 0, stream>>>(bcnt, bucket_base, tails, rowptr,
                                  nbuckets, N, E);

    k_bin<<<(E + BIN_E - 1) / BIN_E, 512, 0, stream>>>(
        src, dst, a_src, a_dst, tails, stage, E, nbuckets);

    k_refine<<<nbuckets, 1024, 0, stream>>>(stage, bucket_base, rowptr,
                                            recs, N, E, nbuckets);

    k_gather<<<(N + 3) / 4, 256, 0, stream>>>(rowptr, recs, a_src, a_dst,
                                              hb, bias, out, N);
}